// Round 14
// baseline (141.935 us; speedup 1.0000x reference)
//
#include <hip/hip_runtime.h>
#include <math.h>

#define BATCH 1024
#define DIM   256
#define NCL   50000
#define TOTC  100000   // 2*NC
#define NSLICE 16
#define K2E   28.853900817779268f   // 20 * log2(e)

typedef __attribute__((ext_vector_type(8)))  short bf16x8;   // 8 bf16 = 4 VGPR
typedef __attribute__((ext_vector_type(16))) float f32x16;   // 32x32 acc frag

__device__ __forceinline__ unsigned int f2bf(float f) {   // RNE f32 -> bf16
    unsigned int u = __float_as_uint(f);
    return (u + 0x7FFFu + ((u >> 16) & 1u)) >> 16;
}

// ---------------------------------------------------------------------------
// Kernel 1: normalize rows; write bf16 xn PRE-SCALED by K2E and TRANSPOSED
// in k-panels (element (k,b) at panel p=k>>3, byte p*16384 + b*16 + (k&7)*2),
// so k_main's MFMA output is already K2E*dot and the epilogue is a bare
// exp2f. Target logits (f32, unscaled path); zero sliced accumulators.
// ---------------------------------------------------------------------------
__global__ __launch_bounds__(64) void k_prep(const float* __restrict__ in,
                                             const int* __restrict__ tgt,
                                             const float* __restrict__ feats,
                                             unsigned short* __restrict__ xnT,
                                             float* __restrict__ Sx,
                                             float* __restrict__ z) {
    const int b = blockIdx.x;
    const int t = threadIdx.x;           // 0..63, 4 floats each (k = t*4..t*4+3)
    float4 v = *(const float4*)&in[b * DIM + t * 4];
    float ss = v.x * v.x + v.y * v.y + v.z * v.z + v.w * v.w;
#pragma unroll
    for (int o = 1; o < 64; o <<= 1) ss += __shfl_xor(ss, o, 64);
    const float sc = 1.0f / sqrtf(ss);
    float4 w;
    w.x = v.x * sc; w.y = v.y * sc; w.z = v.z * sc; w.w = v.w * sc;

    // panel write, scaled by K2E: acc = K2E * dot
    uint2 p;
    p.x = f2bf(w.x * K2E) | (f2bf(w.y * K2E) << 16);
    p.y = f2bf(w.z * K2E) | (f2bf(w.w * K2E) << 16);
    *(uint2*)((char*)xnT + (t >> 1) * 16384 + b * 16 + (t & 1) * 8) = p;

    const int tb = tgt[b];
#pragma unroll
    for (int h = 0; h < 2; ++h) {
        const int row = tb + h * NCL;    // mean half rows [0,NC), hard [NC,2NC)
        float4 f = *(const float4*)&feats[row * DIM + t * 4];
        float d = w.x * f.x + w.y * f.y + w.z * f.z + w.w * f.w;
#pragma unroll
        for (int o = 1; o < 64; o <<= 1) d += __shfl_xor(d, o, 64);
        if (t == 0) z[b * 2 + h] = d * 20.0f;
    }
    if (t < 32) Sx[b * 32 + t] = 0.0f;
}

// ---------------------------------------------------------------------------
// Kernel 2: MFMA GEMM + fused sumexp, with an EXPLICIT depth-4 register
// prefetch queue on the B-stream (the never-fixed latency chain): loads for
// kk+4 issue before kk's MFMAs; during kk=12..15 the queue prefills the
// NEXT p's first chunks, so 8 loads stay in flight even across the
// epilogue. Depth-1 A-prefetch covers LDS latency. 1563 blocks x 4 waves;
// block owns 64 clusters; A staged ONCE panel-major (0 conflicts); ONE
// barrier; atomics once at kernel end.
// ---------------------------------------------------------------------------
__global__ __launch_bounds__(256) void k_main(const unsigned short* __restrict__ xnT,
                                              const float* __restrict__ feats,
                                              float* __restrict__ Sx) {
    __shared__ unsigned short Ab[64 * 256];   // 32 KB, block-lifetime constant

    const int tid  = threadIdx.x;
    const int lane = tid & 63;
    const int wn   = tid >> 6;        // 0..3: wave's 64-col group
    const int l31  = lane & 31;
    const int hi   = lane >> 5;       // 0/1
    const int cb0  = blockIdx.x * 64;
    float* Ss = Sx + (blockIdx.x & (NSLICE - 1)) * (BATCH * 2);

    // ---- stage A panel-major: (row r, chunk c) -> byte c*1024 + ((r*16)^((c&7)<<4))
#pragma unroll
    for (int it = 0; it < 8; ++it) {
        const int idx = it * 256 + tid;      // 2048 tasks = 64 rows x 32 chunks
        const int r = idx >> 5;              // 0..63
        const int c = idx & 31;              // chunk (8 bf16 = 16B)
        int gr = cb0 + r;
        if (gr > TOTC - 1) gr = TOTC - 1;    // clamp; masked in epilogue
        const float4 f0 = *(const float4*)&feats[(size_t)gr * DIM + c * 8];
        const float4 f1 = *(const float4*)&feats[(size_t)gr * DIM + c * 8 + 4];
        uint4 pk;
        pk.x = f2bf(f0.x) | (f2bf(f0.y) << 16);
        pk.y = f2bf(f0.z) | (f2bf(f0.w) << 16);
        pk.z = f2bf(f1.x) | (f2bf(f1.y) << 16);
        pk.w = f2bf(f1.z) | (f2bf(f1.w) << 16);
        *(uint4*)((char*)Ab + c * 1024 + ((r * 16) ^ ((c & 7) << 4))) = pk;
    }
    __syncthreads();                         // the ONLY barrier in this kernel

    const bool mixed = (cb0 < NCL && cb0 + 63 >= NCL) || (cb0 + 63 >= TOTC);
    const int  halfsel = (cb0 >= NCL) ? 1 : 0;

    // A-fragment macro (panel-major, swizzled)
#define LDA(mt_, kv_) (*(const bf16x8*)((const char*)Ab + ((kv_)*2 + hi) * 1024 \
                        + ((((mt_)*512) + l31*16) ^ (((((kv_)*2 + hi)) & 7) << 4))))

    // B bases: col*8 + hi*8192, kk stride 16384 ushorts; p stride 2048 (256 cols)
    const unsigned short* bp0 = xnT + (size_t)hi * 8192 + (size_t)(wn * 64 + l31) * 8;
    const unsigned short* bp1 = bp0 + 256;   // +32 cols

    float sr0[4][2], sr1[4][2];

    // ---- prefill queue for p=0 (depth 4) ----
    bf16x8 q0[4], q1[4];
#pragma unroll
    for (int i = 0; i < 4; ++i) {
        q0[i] = *(const bf16x8*)(bp0 + (size_t)i * 16384);
        q1[i] = *(const bf16x8*)(bp1 + (size_t)i * 16384);
    }

#pragma unroll
    for (int p = 0; p < 4; ++p) {
        const unsigned short* bc0 = bp0 + (size_t)p * 2048;
        const unsigned short* bc1 = bp1 + (size_t)p * 2048;

        f32x16 acc[2][2];
#pragma unroll
        for (int mt = 0; mt < 2; ++mt) {
            acc[mt][0] = (f32x16)(0.0f);
            acc[mt][1] = (f32x16)(0.0f);
        }

        bf16x8 a0c = LDA(0, 0);
        bf16x8 a1c = LDA(1, 0);

#pragma unroll
        for (int kk = 0; kk < 16; ++kk) {
            const bf16x8 b0 = q0[kk & 3];
            const bf16x8 b1 = q1[kk & 3];
            bf16x8 a0n, a1n;
            if (kk < 15) {                       // depth-1 A prefetch (LDS)
                a0n = LDA(0, kk + 1);
                a1n = LDA(1, kk + 1);
            }
            if (kk < 12) {                       // refill depth-4 B queue
                q0[kk & 3] = *(const bf16x8*)(bc0 + (size_t)(kk + 4) * 16384);
                q1[kk & 3] = *(const bf16x8*)(bc1 + (size_t)(kk + 4) * 16384);
            } else if (p < 3) {                  // prefill NEXT p across epilogue
                q0[kk & 3] = *(const bf16x8*)(bc0 + 2048 + (size_t)(kk - 12) * 16384);
                q1[kk & 3] = *(const bf16x8*)(bc1 + 2048 + (size_t)(kk - 12) * 16384);
            }
            acc[0][0] = __builtin_amdgcn_mfma_f32_32x32x16_bf16(a0c, b0, acc[0][0], 0, 0, 0);
            acc[0][1] = __builtin_amdgcn_mfma_f32_32x32x16_bf16(a0c, b1, acc[0][1], 0, 0, 0);
            acc[1][0] = __builtin_amdgcn_mfma_f32_32x32x16_bf16(a1c, b0, acc[1][0], 0, 0, 0);
            acc[1][1] = __builtin_amdgcn_mfma_f32_32x32x16_bf16(a1c, b1, acc[1][1], 0, 0, 0);
            if (kk < 15) { a0c = a0n; a1c = a1n; }
        }

        // ---- epilogue: e = exp2(acc) == exp(20d); sum over 64 cluster rows
        if (!mixed) {
#pragma unroll
            for (int nn = 0; nn < 2; ++nn) {
                float sa = 0.0f, sb = 0.0f;
#pragma unroll
                for (int r = 0; r < 16; ++r) {
                    sa += exp2f(acc[0][nn][r]);
                    sb += exp2f(acc[1][nn][r]);
                }
                float s = sa + sb;
                s += __shfl_xor(s, 32, 64);    // combine hi halves (rows +4)
                sr0[p][nn] = s;
                sr1[p][nn] = 0.0f;
            }
        } else {
#pragma unroll
            for (int nn = 0; nn < 2; ++nn) {
                float sh0 = 0.0f, sh1 = 0.0f;
#pragma unroll
                for (int mt = 0; mt < 2; ++mt)
#pragma unroll
                    for (int r = 0; r < 16; ++r) {
                        const int cl = cb0 + mt * 32 +
                                       (r & 3) + 8 * (r >> 2) + 4 * hi;
                        const bool valid = cl < TOTC;
                        float e = exp2f(acc[mt][nn][r]);
                        e = valid ? e : 0.0f;
                        sh0 += (cl < NCL) ? e : 0.0f;
                        sh1 += (cl < NCL) ? 0.0f : e;
                    }
                sh0 += __shfl_xor(sh0, 32, 64);
                sh1 += __shfl_xor(sh1, 32, 64);
                sr0[p][nn] = sh0;
                sr1[p][nn] = sh1;
            }
        }
    }
#undef LDA

    // ---- all atomics at the very end: fire-and-forget ----
    if (hi == 0) {
#pragma unroll
        for (int p = 0; p < 4; ++p)
#pragma unroll
            for (int nn = 0; nn < 2; ++nn) {
                const int col = p * 256 + wn * 64 + nn * 32 + l31;
                if (!mixed) {
                    atomicAdd(&Ss[col * 2 + halfsel], sr0[p][nn]);
                } else {
                    atomicAdd(&Ss[col * 2 + 0], sr0[p][nn]);
                    atomicAdd(&Ss[col * 2 + 1], sr1[p][nn]);
                }
            }
    }
}

// ---------------------------------------------------------------------------
// Kernel 3: S_new = e^{20} * S_old; the "+20" shifts cancel the old +40:
// loss = 0.5 * mean_b[ log S0_new + log S1_new - z0 - z1 ]
// ---------------------------------------------------------------------------
__global__ __launch_bounds__(256) void k_loss(const float* __restrict__ Sx,
                                              const float* __restrict__ z,
                                              float* __restrict__ out) {
    const int t = threadIdx.x;
    float part = 0.0f;
    for (int r = t; r < BATCH; r += 256) {
        float s0 = 0.0f, s1 = 0.0f;
#pragma unroll
        for (int sl = 0; sl < NSLICE; ++sl) {
            s0 += Sx[sl * (BATCH * 2) + r * 2 + 0];
            s1 += Sx[sl * (BATCH * 2) + r * 2 + 1];
        }
        part += logf(s0) + logf(s1) - z[r * 2 + 0] - z[r * 2 + 1];
    }
#pragma unroll
    for (int o = 1; o < 64; o <<= 1) part += __shfl_xor(part, o, 64);
    __shared__ float ws[4];
    if ((t & 63) == 0) ws[t >> 6] = part;
    __syncthreads();
    if (t == 0) {
        const float tot = ws[0] + ws[1] + ws[2] + ws[3];
        out[0] = 0.5f * tot / (float)BATCH;
    }
}

// ---------------------------------------------------------------------------
extern "C" void kernel_launch(void* const* d_in, const int* in_sizes, int n_in,
                              void* d_out, int out_size, void* d_ws, size_t ws_size,
                              hipStream_t stream) {
    const float* inputs  = (const float*)d_in[0];
    const int*   targets = (const int*)d_in[1];
    const float* feats   = (const float*)d_in[2];
    float* out = (float*)d_out;

    unsigned short* xnT = (unsigned short*)d_ws;          // 32 panels * 16 KB = 512 KB
    float* Sx = (float*)(xnT + BATCH * DIM);              // 16*1024*2 f32 = 128 KB
    float* zt = Sx + NSLICE * BATCH * 2;                  // 1024*2 f32

    k_prep<<<BATCH, 64, 0, stream>>>(inputs, targets, feats, xnT, Sx, zt);
    const int nblk = (TOTC + 63) / 64;                    // 1563
    k_main<<<nblk, 256, 0, stream>>>(xnT, feats, Sx);
    k_loss<<<1, 256, 0, stream>>>(Sx, zt, out);
}

// Round 15
// 117.810 us; speedup vs baseline: 1.2048x; 1.2048x over previous
//
#include <hip/hip_runtime.h>
#include <math.h>

#define BATCH 1024
#define DIM   256
#define NCL   50000
#define TOTC  100000   // 2*NC
#define NSLICE 16
#define K2E   28.853900817779268f   // 20 * log2(e)

typedef __attribute__((ext_vector_type(8)))  short bf16x8;   // 8 bf16 = 4 VGPR
typedef __attribute__((ext_vector_type(16))) float f32x16;   // 32x32 acc frag

__device__ __forceinline__ unsigned int f2bf(float f) {   // RNE f32 -> bf16
    unsigned int u = __float_as_uint(f);
    return (u + 0x7FFFu + ((u >> 16) & 1u)) >> 16;
}

// ---------------------------------------------------------------------------
// Kernel 1: normalize rows; write bf16 xn PRE-SCALED by K2E and TRANSPOSED
// in k-panels (element (k,b) at panel p=k>>3, byte p*16384 + b*16 + (k&7)*2),
// so k_main's MFMA output is already K2E*dot and the epilogue is a bare
// exp2f. Target logits (f32, unscaled path); zero sliced accumulators.
// ---------------------------------------------------------------------------
__global__ __launch_bounds__(64) void k_prep(const float* __restrict__ in,
                                             const int* __restrict__ tgt,
                                             const float* __restrict__ feats,
                                             unsigned short* __restrict__ xnT,
                                             float* __restrict__ Sx,
                                             float* __restrict__ z) {
    const int b = blockIdx.x;
    const int t = threadIdx.x;           // 0..63, 4 floats each (k = t*4..t*4+3)
    float4 v = *(const float4*)&in[b * DIM + t * 4];
    float ss = v.x * v.x + v.y * v.y + v.z * v.z + v.w * v.w;
#pragma unroll
    for (int o = 1; o < 64; o <<= 1) ss += __shfl_xor(ss, o, 64);
    const float sc = 1.0f / sqrtf(ss);
    float4 w;
    w.x = v.x * sc; w.y = v.y * sc; w.z = v.z * sc; w.w = v.w * sc;

    // panel write, scaled by K2E: acc = K2E * dot
    uint2 p;
    p.x = f2bf(w.x * K2E) | (f2bf(w.y * K2E) << 16);
    p.y = f2bf(w.z * K2E) | (f2bf(w.w * K2E) << 16);
    *(uint2*)((char*)xnT + (t >> 1) * 16384 + b * 16 + (t & 1) * 8) = p;

    const int tb = tgt[b];
#pragma unroll
    for (int h = 0; h < 2; ++h) {
        const int row = tb + h * NCL;    // mean half rows [0,NC), hard [NC,2NC)
        float4 f = *(const float4*)&feats[row * DIM + t * 4];
        float d = w.x * f.x + w.y * f.y + w.z * f.z + w.w * f.w;
#pragma unroll
        for (int o = 1; o < 64; o <<= 1) d += __shfl_xor(d, o, 64);
        if (t == 0) z[b * 2 + h] = d * 20.0f;
    }
    if (t < 32) Sx[b * 32 + t] = 0.0f;
}

// ---------------------------------------------------------------------------
// Kernel 2: MFMA GEMM + fused sumexp. The kk loop contains ZERO global
// memory operations: at each pass start, the wave burst-loads its entire
// 64-col x K=256 B-panel into 128 VGPRs (32 independent coalesced 16B
// loads -> one latency exposure per pass, not 64 chained ones). Loop body
// = 2 ds_read_b128 + 4 MFMA. 1563 blocks x 4 waves; block owns 64
// clusters; A staged ONCE panel-major (0 conflicts); ONE barrier.
// ~230 unified regs -> 2 waves/SIMD = 2 co-resident blocks/CU cover the
// bursts and epilogue. Pure blocks: sums in regs, atomics at kernel end.
// The 2 mixed boundary blocks take an immediate-atomic slow path.
// ---------------------------------------------------------------------------
__global__ __launch_bounds__(256) void k_main(const unsigned short* __restrict__ xnT,
                                              const float* __restrict__ feats,
                                              float* __restrict__ Sx) {
    __shared__ unsigned short Ab[64 * 256];   // 32 KB, block-lifetime constant

    const int tid  = threadIdx.x;
    const int lane = tid & 63;
    const int wn   = tid >> 6;        // 0..3: wave's 64-col group
    const int l31  = lane & 31;
    const int hi   = lane >> 5;       // 0/1
    const int cb0  = blockIdx.x * 64;
    float* Ss = Sx + (blockIdx.x & (NSLICE - 1)) * (BATCH * 2);

    // ---- stage A panel-major: (row r, chunk c) -> byte c*1024 + ((r*16)^((c&7)<<4))
#pragma unroll
    for (int it = 0; it < 8; ++it) {
        const int idx = it * 256 + tid;      // 2048 tasks = 64 rows x 32 chunks
        const int r = idx >> 5;              // 0..63
        const int c = idx & 31;              // chunk (8 bf16 = 16B)
        int gr = cb0 + r;
        if (gr > TOTC - 1) gr = TOTC - 1;    // clamp; masked in epilogue
        const float4 f0 = *(const float4*)&feats[(size_t)gr * DIM + c * 8];
        const float4 f1 = *(const float4*)&feats[(size_t)gr * DIM + c * 8 + 4];
        uint4 pk;
        pk.x = f2bf(f0.x) | (f2bf(f0.y) << 16);
        pk.y = f2bf(f0.z) | (f2bf(f0.w) << 16);
        pk.z = f2bf(f1.x) | (f2bf(f1.y) << 16);
        pk.w = f2bf(f1.z) | (f2bf(f1.w) << 16);
        *(uint4*)((char*)Ab + c * 1024 + ((r * 16) ^ ((c & 7) << 4))) = pk;
    }
    __syncthreads();                         // the ONLY barrier in this kernel

    const bool mixed = (cb0 < NCL && cb0 + 63 >= NCL) || (cb0 + 63 >= TOTC);
    const int  halfsel = (cb0 >= NCL) ? 1 : 0;

    // A-fragment macro (panel-major, swizzled)
#define LDA(mt_, kv_) (*(const bf16x8*)((const char*)Ab + ((kv_)*2 + hi) * 1024 \
                        + ((((mt_)*512) + l31*16) ^ (((((kv_)*2 + hi)) & 7) << 4))))

    // B bases: col*8 + hi*8192; kk stride 16384 ushorts; p stride 2048 (256 cols)
    const unsigned short* bp0 = xnT + (size_t)hi * 8192 + (size_t)(wn * 64 + l31) * 8;
    const unsigned short* bp1 = bp0 + 256;   // +32 cols

    float sr[4][2];

#pragma unroll
    for (int p = 0; p < 4; ++p) {
        const unsigned short* bc0 = bp0 + (size_t)p * 2048;
        const unsigned short* bc1 = bp1 + (size_t)p * 2048;

        // ---- burst-load this pass's full B-panel into registers ----
        bf16x8 breg0[16], breg1[16];
#pragma unroll
        for (int kk = 0; kk < 16; ++kk) {
            breg0[kk] = *(const bf16x8*)(bc0 + (size_t)kk * 16384);
            breg1[kk] = *(const bf16x8*)(bc1 + (size_t)kk * 16384);
        }

        f32x16 acc00 = (f32x16)(0.0f), acc01 = (f32x16)(0.0f);
        f32x16 acc10 = (f32x16)(0.0f), acc11 = (f32x16)(0.0f);

        // ---- kk loop: 2 ds_read_b128 + 4 MFMA, nothing else ----
#pragma unroll
        for (int kk = 0; kk < 16; ++kk) {
            const bf16x8 a0 = LDA(0, kk);
            const bf16x8 a1 = LDA(1, kk);
            acc00 = __builtin_amdgcn_mfma_f32_32x32x16_bf16(a0, breg0[kk], acc00, 0, 0, 0);
            acc01 = __builtin_amdgcn_mfma_f32_32x32x16_bf16(a0, breg1[kk], acc01, 0, 0, 0);
            acc10 = __builtin_amdgcn_mfma_f32_32x32x16_bf16(a1, breg0[kk], acc10, 0, 0, 0);
            acc11 = __builtin_amdgcn_mfma_f32_32x32x16_bf16(a1, breg1[kk], acc11, 0, 0, 0);
        }

        // ---- epilogue: e = exp2(acc) == exp(20d); sum over 64 cluster rows
        if (!mixed) {
            float s0 = 0.0f, s1 = 0.0f;
#pragma unroll
            for (int r = 0; r < 16; ++r) {
                s0 += exp2f(acc00[r]);
                s0 += exp2f(acc10[r]);
                s1 += exp2f(acc01[r]);
                s1 += exp2f(acc11[r]);
            }
            s0 += __shfl_xor(s0, 32, 64);    // combine hi halves (rows +4)
            s1 += __shfl_xor(s1, 32, 64);
            sr[p][0] = s0;
            sr[p][1] = s1;
        } else {
            // boundary blocks (2 of 1563): immediate atomics, per-element masks
#pragma unroll
            for (int nn = 0; nn < 2; ++nn) {
                float sh0 = 0.0f, sh1 = 0.0f;
#pragma unroll
                for (int mt = 0; mt < 2; ++mt)
#pragma unroll
                    for (int r = 0; r < 16; ++r) {
                        const int cl = cb0 + mt * 32 + (r & 3) + 8 * (r >> 2) + 4 * hi;
                        const bool valid = cl < TOTC;
                        float e = exp2f(mt ? (nn ? acc11[r] : acc10[r])
                                           : (nn ? acc01[r] : acc00[r]));
                        e = valid ? e : 0.0f;
                        sh0 += (cl < NCL) ? e : 0.0f;
                        sh1 += (cl < NCL) ? 0.0f : e;
                    }
                sh0 += __shfl_xor(sh0, 32, 64);
                sh1 += __shfl_xor(sh1, 32, 64);
                if (hi == 0) {
                    const int col = p * 256 + wn * 64 + nn * 32 + l31;
                    atomicAdd(&Ss[col * 2 + 0], sh0);
                    atomicAdd(&Ss[col * 2 + 1], sh1);
                }
            }
        }
    }
#undef LDA

    // ---- pure blocks: all atomics at the very end, fire-and-forget ----
    if (!mixed && hi == 0) {
#pragma unroll
        for (int p = 0; p < 4; ++p)
#pragma unroll
            for (int nn = 0; nn < 2; ++nn) {
                const int col = p * 256 + wn * 64 + nn * 32 + l31;
                atomicAdd(&Ss[col * 2 + halfsel], sr[p][nn]);
            }
    }
}

// ---------------------------------------------------------------------------
// Kernel 3: S_new = e^{20} * S_old; the "+20" shifts cancel the old +40:
// loss = 0.5 * mean_b[ log S0_new + log S1_new - z0 - z1 ]
// ---------------------------------------------------------------------------
__global__ __launch_bounds__(256) void k_loss(const float* __restrict__ Sx,
                                              const float* __restrict__ z,
                                              float* __restrict__ out) {
    const int t = threadIdx.x;
    float part = 0.0f;
    for (int r = t; r < BATCH; r += 256) {
        float s0 = 0.0f, s1 = 0.0f;
#pragma unroll
        for (int sl = 0; sl < NSLICE; ++sl) {
            s0 += Sx[sl * (BATCH * 2) + r * 2 + 0];
            s1 += Sx[sl * (BATCH * 2) + r * 2 + 1];
        }
        part += logf(s0) + logf(s1) - z[r * 2 + 0] - z[r * 2 + 1];
    }
#pragma unroll
    for (int o = 1; o < 64; o <<= 1) part += __shfl_xor(part, o, 64);
    __shared__ float ws[4];
    if ((t & 63) == 0) ws[t >> 6] = part;
    __syncthreads();
    if (t == 0) {
        const float tot = ws[0] + ws[1] + ws[2] + ws[3];
        out[0] = 0.5f * tot / (float)BATCH;
    }
}

// ---------------------------------------------------------------------------
extern "C" void kernel_launch(void* const* d_in, const int* in_sizes, int n_in,
                              void* d_out, int out_size, void* d_ws, size_t ws_size,
                              hipStream_t stream) {
    const float* inputs  = (const float*)d_in[0];
    const int*   targets = (const int*)d_in[1];
    const float* feats   = (const float*)d_in[2];
    float* out = (float*)d_out;

    unsigned short* xnT = (unsigned short*)d_ws;          // 32 panels * 16 KB = 512 KB
    float* Sx = (float*)(xnT + BATCH * DIM);              // 16*1024*2 f32 = 128 KB
    float* zt = Sx + NSLICE * BATCH * 2;                  // 1024*2 f32

    k_prep<<<BATCH, 64, 0, stream>>>(inputs, targets, feats, xnT, Sx, zt);
    const int nblk = (TOTC + 63) / 64;                    // 1563
    k_main<<<nblk, 256, 0, stream>>>(xnT, feats, Sx);
    k_loss<<<1, 256, 0, stream>>>(Sx, zt, out);
}

// Round 16
// 97.700 us; speedup vs baseline: 1.4528x; 1.2058x over previous
//
#include <hip/hip_runtime.h>
#include <math.h>

#define BATCH 1024
#define DIM   256
#define NCL   50000
#define TOTC  100000   // 2*NC
#define NSLICE 16
#define K2E   28.853900817779268f   // 20 * log2(e)

typedef __attribute__((ext_vector_type(8)))  short bf16x8;   // 8 bf16 = 4 VGPR
typedef __attribute__((ext_vector_type(16))) float f32x16;   // 32x32 acc frag

__device__ __forceinline__ unsigned int f2bf(float f) {   // RNE f32 -> bf16
    unsigned int u = __float_as_uint(f);
    return (u + 0x7FFFu + ((u >> 16) & 1u)) >> 16;
}

// ---------------------------------------------------------------------------
// Kernel 1: normalize rows; write bf16 xn PRE-SCALED by K2E in COL-BLOCK-
// MAJOR layout: element (k,b) at ushort index
//   (b>>5)*8192 + (k>>3)*256 + (b&31)*8 + (k&7)
// A 32-lane B-fragment (cols b0..b0+31, k = ch*8..ch*8+7) is then 512 B
// contiguous, and CONSECUTIVE kk fragments are 1 KB apart: a wave's whole
// pass streams one 16 KB window sequentially (L1-capturable; co-resident
// blocks reading the same window hit L1). Also: target logits, zero
// sliced accumulators.
// ---------------------------------------------------------------------------
__global__ __launch_bounds__(64) void k_prep(const float* __restrict__ in,
                                             const int* __restrict__ tgt,
                                             const float* __restrict__ feats,
                                             unsigned short* __restrict__ xnT,
                                             float* __restrict__ Sx,
                                             float* __restrict__ z) {
    const int b = blockIdx.x;
    const int t = threadIdx.x;           // 0..63, 4 floats each (k = t*4..t*4+3)
    float4 v = *(const float4*)&in[b * DIM + t * 4];
    float ss = v.x * v.x + v.y * v.y + v.z * v.z + v.w * v.w;
#pragma unroll
    for (int o = 1; o < 64; o <<= 1) ss += __shfl_xor(ss, o, 64);
    const float sc = 1.0f / sqrtf(ss);
    float4 w;
    w.x = v.x * sc; w.y = v.y * sc; w.z = v.z * sc; w.w = v.w * sc;

    // col-block-major write, scaled by K2E: 4 ushorts (uint2) per thread
    uint2 p;
    p.x = f2bf(w.x * K2E) | (f2bf(w.y * K2E) << 16);
    p.y = f2bf(w.z * K2E) | (f2bf(w.w * K2E) << 16);
    const size_t ui = (size_t)(b >> 5) * 8192 + (t >> 1) * 256 + (b & 31) * 8 + (t & 1) * 4;
    *(uint2*)(xnT + ui) = p;

    const int tb = tgt[b];
#pragma unroll
    for (int h = 0; h < 2; ++h) {
        const int row = tb + h * NCL;    // mean half rows [0,NC), hard [NC,2NC)
        float4 f = *(const float4*)&feats[row * DIM + t * 4];
        float d = w.x * f.x + w.y * f.y + w.z * f.z + w.w * f.w;
#pragma unroll
        for (int o = 1; o < 64; o <<= 1) d += __shfl_xor(d, o, 64);
        if (t == 0) z[b * 2 + h] = d * 20.0f;
    }
    if (t < 32) Sx[b * 32 + t] = 0.0f;
}

// ---------------------------------------------------------------------------
// Kernel 2: MFMA GEMM + fused sumexp. 1563 blocks x 4 waves; block owns 64
// clusters; A staged ONCE panel-major into 32 KB LDS (0 conflicts); ONE
// barrier. Per pass, the wave streams its two 16 KB B col-blocks
// SEQUENTIALLY (1 KB kk-stride) with a depth-2 named-scalar prefetch
// (loads 2 kk ahead, 16 VGPR cost; no arrays -> no R14/R15 reg pathology).
// __launch_bounds__(256,3) caps regs at 168. Sums -> static sregs; atomics
// once at kernel end (pure blocks); 2 mixed boundary blocks take the
// immediate-atomic path.
// ---------------------------------------------------------------------------
__global__ __launch_bounds__(256, 3) void k_main(const unsigned short* __restrict__ xnT,
                                                 const float* __restrict__ feats,
                                                 float* __restrict__ Sx) {
    __shared__ unsigned short Ab[64 * 256];   // 32 KB, block-lifetime constant

    const int tid  = threadIdx.x;
    const int lane = tid & 63;
    const int wn   = tid >> 6;        // 0..3: wave's 64-col group
    const int l31  = lane & 31;
    const int hi   = lane >> 5;       // 0/1
    const int cb0  = blockIdx.x * 64;
    float* Ss = Sx + (blockIdx.x & (NSLICE - 1)) * (BATCH * 2);

    // ---- stage A panel-major: (row r, chunk c) -> byte c*1024 + ((r*16)^((c&7)<<4))
#pragma unroll
    for (int it = 0; it < 8; ++it) {
        const int idx = it * 256 + tid;      // 2048 tasks = 64 rows x 32 chunks
        const int r = idx >> 5;              // 0..63
        const int c = idx & 31;              // chunk (8 bf16 = 16B)
        int gr = cb0 + r;
        if (gr > TOTC - 1) gr = TOTC - 1;    // clamp; masked in epilogue
        const float4 f0 = *(const float4*)&feats[(size_t)gr * DIM + c * 8];
        const float4 f1 = *(const float4*)&feats[(size_t)gr * DIM + c * 8 + 4];
        uint4 pk;
        pk.x = f2bf(f0.x) | (f2bf(f0.y) << 16);
        pk.y = f2bf(f0.z) | (f2bf(f0.w) << 16);
        pk.z = f2bf(f1.x) | (f2bf(f1.y) << 16);
        pk.w = f2bf(f1.z) | (f2bf(f1.w) << 16);
        *(uint4*)((char*)Ab + c * 1024 + ((r * 16) ^ ((c & 7) << 4))) = pk;
    }
    __syncthreads();                         // the ONLY barrier in this kernel

    const bool mixed = (cb0 < NCL && cb0 + 63 >= NCL) || (cb0 + 63 >= TOTC);
    const int  halfsel = (cb0 >= NCL) ? 1 : 0;

    // A-fragment macro (panel-major, swizzled)
#define LDA(mt_, kv_) (*(const bf16x8*)((const char*)Ab + ((kv_)*2 + hi) * 1024 \
                        + ((((mt_)*512) + l31*16) ^ (((((kv_)*2 + hi)) & 7) << 4))))
    // B-fragment: col-block cb, kk step -> ushort offset (kk*2+hi)*256 + l31*8
#define LDB(base_, kv_) (*(const bf16x8*)((base_) + (size_t)(kv_) * 512))

    float sr[4][2];

#pragma unroll
    for (int p = 0; p < 4; ++p) {
        // two 16 KB col-block windows for this wave (cols p*256+wn*64 .. +63)
        const unsigned short* q0 = xnT + (size_t)(p * 8 + wn * 2 + 0) * 8192
                                 + (size_t)hi * 256 + l31 * 8;
        const unsigned short* q1 = q0 + 8192;   // next col-block (+32 cols)

        f32x16 acc00 = (f32x16)(0.0f), acc01 = (f32x16)(0.0f);
        f32x16 acc10 = (f32x16)(0.0f), acc11 = (f32x16)(0.0f);

        // ---- depth-2 prefetch, named scalars only ----
        bf16x8 b0c = LDB(q0, 0), b1c = LDB(q1, 0);
        bf16x8 b0n = LDB(q0, 1), b1n = LDB(q1, 1);

#pragma unroll
        for (int kk = 0; kk < 16; ++kk) {
            const bf16x8 a0 = LDA(0, kk);
            const bf16x8 a1 = LDA(1, kk);
            acc00 = __builtin_amdgcn_mfma_f32_32x32x16_bf16(a0, b0c, acc00, 0, 0, 0);
            acc10 = __builtin_amdgcn_mfma_f32_32x32x16_bf16(a1, b0c, acc10, 0, 0, 0);
            acc01 = __builtin_amdgcn_mfma_f32_32x32x16_bf16(a0, b1c, acc01, 0, 0, 0);
            acc11 = __builtin_amdgcn_mfma_f32_32x32x16_bf16(a1, b1c, acc11, 0, 0, 0);
            b0c = b0n; b1c = b1n;
            if (kk < 14) {
                b0n = LDB(q0, kk + 2);
                b1n = LDB(q1, kk + 2);
            }
        }

        // ---- epilogue: e = exp2(acc) == exp(20d); sum over 64 cluster rows
        if (!mixed) {
            float s0 = 0.0f, s1 = 0.0f;
#pragma unroll
            for (int r = 0; r < 16; ++r) {
                s0 += exp2f(acc00[r]);
                s0 += exp2f(acc10[r]);
                s1 += exp2f(acc01[r]);
                s1 += exp2f(acc11[r]);
            }
            s0 += __shfl_xor(s0, 32, 64);    // combine hi halves (rows +4)
            s1 += __shfl_xor(s1, 32, 64);
            sr[p][0] = s0;
            sr[p][1] = s1;
        } else {
            // boundary blocks (2 of 1563): immediate atomics, per-element masks
#pragma unroll
            for (int nn = 0; nn < 2; ++nn) {
                float sh0 = 0.0f, sh1 = 0.0f;
#pragma unroll
                for (int mt = 0; mt < 2; ++mt)
#pragma unroll
                    for (int r = 0; r < 16; ++r) {
                        const int cl = cb0 + mt * 32 + (r & 3) + 8 * (r >> 2) + 4 * hi;
                        const bool valid = cl < TOTC;
                        float e = exp2f(mt ? (nn ? acc11[r] : acc10[r])
                                           : (nn ? acc01[r] : acc00[r]));
                        e = valid ? e : 0.0f;
                        sh0 += (cl < NCL) ? e : 0.0f;
                        sh1 += (cl < NCL) ? 0.0f : e;
                    }
                sh0 += __shfl_xor(sh0, 32, 64);
                sh1 += __shfl_xor(sh1, 32, 64);
                if (hi == 0) {
                    const int col = p * 256 + wn * 64 + nn * 32 + l31;
                    atomicAdd(&Ss[col * 2 + 0], sh0);
                    atomicAdd(&Ss[col * 2 + 1], sh1);
                }
            }
        }
    }
#undef LDA
#undef LDB

    // ---- pure blocks: all atomics at the very end, fire-and-forget ----
    if (!mixed && hi == 0) {
#pragma unroll
        for (int p = 0; p < 4; ++p)
#pragma unroll
            for (int nn = 0; nn < 2; ++nn) {
                const int col = p * 256 + wn * 64 + nn * 32 + l31;
                atomicAdd(&Ss[col * 2 + halfsel], sr[p][nn]);
            }
    }
}

// ---------------------------------------------------------------------------
// Kernel 3: S_new = e^{20} * S_old; the "+20" shifts cancel the old +40:
// loss = 0.5 * mean_b[ log S0_new + log S1_new - z0 - z1 ]
// ---------------------------------------------------------------------------
__global__ __launch_bounds__(256) void k_loss(const float* __restrict__ Sx,
                                              const float* __restrict__ z,
                                              float* __restrict__ out) {
    const int t = threadIdx.x;
    float part = 0.0f;
    for (int r = t; r < BATCH; r += 256) {
        float s0 = 0.0f, s1 = 0.0f;
#pragma unroll
        for (int sl = 0; sl < NSLICE; ++sl) {
            s0 += Sx[sl * (BATCH * 2) + r * 2 + 0];
            s1 += Sx[sl * (BATCH * 2) + r * 2 + 1];
        }
        part += logf(s0) + logf(s1) - z[r * 2 + 0] - z[r * 2 + 1];
    }
#pragma unroll
    for (int o = 1; o < 64; o <<= 1) part += __shfl_xor(part, o, 64);
    __shared__ float ws[4];
    if ((t & 63) == 0) ws[t >> 6] = part;
    __syncthreads();
    if (t == 0) {
        const float tot = ws[0] + ws[1] + ws[2] + ws[3];
        out[0] = 0.5f * tot / (float)BATCH;
    }
}

// ---------------------------------------------------------------------------
extern "C" void kernel_launch(void* const* d_in, const int* in_sizes, int n_in,
                              void* d_out, int out_size, void* d_ws, size_t ws_size,
                              hipStream_t stream) {
    const float* inputs  = (const float*)d_in[0];
    const int*   targets = (const int*)d_in[1];
    const float* feats   = (const float*)d_in[2];
    float* out = (float*)d_out;

    unsigned short* xnT = (unsigned short*)d_ws;          // 512 KB (col-block-major)
    float* Sx = (float*)(xnT + BATCH * DIM);              // 16*1024*2 f32 = 128 KB
    float* zt = Sx + NSLICE * BATCH * 2;                  // 1024*2 f32

    k_prep<<<BATCH, 64, 0, stream>>>(inputs, targets, feats, xnT, Sx, zt);
    const int nblk = (TOTC + 63) / 64;                    // 1563
    k_main<<<nblk, 256, 0, stream>>>(xnT, feats, Sx);
    k_loss<<<1, 256, 0, stream>>>(Sx, zt, out);
}